// Round 10
// baseline (389.970 us; speedup 1.0000x reference)
//
#include <hip/hip_runtime.h>
#include <math.h>

// Problem constants
#define T_ENC 50
#define T_DEC 60
#define HID   128
#define EMB   64
#define DIN   2
#define MT    16      // batch rows per block
#define NTHR  512     // 8 waves, 1 block/CU -> 2 waves/SIMD
#define HS    136     // shorts per h row (pad breaks power-of-2 bank stride)

typedef __attribute__((ext_vector_type(8))) short frag8;  // 8 bf16 (4 VGPRs)
typedef __attribute__((ext_vector_type(4))) float f32x4;  // 4 fp32 acc

__device__ __forceinline__ float fast_rcp(float x) { return __builtin_amdgcn_rcpf(x); }
__device__ __forceinline__ float sigm(float x) { return fast_rcp(1.f + __expf(-x)); }
__device__ __forceinline__ float tanh_fast(float x) { return fmaf(2.f, fast_rcp(1.f + __expf(-2.f * x)), -1.f); }

// Split 8 consecutive floats W[n][kb..kb+7] into hi/lo bf16 fragment registers.
__device__ __forceinline__ void load_wfrag(const float* __restrict__ wrow,
                                           frag8& Fhi, frag8& Flo) {
    union { unsigned short s[8]; frag8 f; } hi, lo;
#pragma unroll
    for (int j = 0; j < 8; ++j) {
        float x      = wrow[j];
        unsigned u   = __float_as_uint(x);
        unsigned uhi = u & 0xffff0000u;
        float    lof = x - __uint_as_float(uhi);   // exact remainder
        hi.s[j] = (unsigned short)(uhi >> 16);
        lo.s[j] = (unsigned short)(__float_as_uint(lof) >> 16);
    }
    Fhi = hi.f; Flo = lo.f;
}

__device__ __forceinline__ void split2(float x, unsigned short& hi, unsigned short& lo) {
    unsigned u   = __float_as_uint(x);
    unsigned uhi = u & 0xffff0000u;
    float    lof = x - __uint_as_float(uhi);
    hi = (unsigned short)(uhi >> 16);
    lo = (unsigned short)(__float_as_uint(lof) >> 16);
}

__global__ __launch_bounds__(NTHR, 2) void lstm_all(
    const float* __restrict__ history,  // (B, 50, 2)
    const float* __restrict__ W_emb,    // (64, 2)
    const float* __restrict__ b_emb,    // (64)
    const float* __restrict__ W_ih,     // (512, 64)
    const float* __restrict__ W_hh,     // (512, 128)
    const float* __restrict__ b_ih,     // (512)
    const float* __restrict__ b_hh,     // (512)
    const float* __restrict__ W1,       // (128, 128)
    const float* __restrict__ b1,       // (128)
    const float* __restrict__ w2,       // (2, 128)
    const float* __restrict__ b2,       // (2)
    float* __restrict__ out)            // (B, 60, 2)
{
    __shared__ __align__(16) unsigned short hhi[2][MT * HS];   // 8.7 KB
    __shared__ __align__(16) unsigned short hlo[2][MT * HS];   // 8.7 KB
    __shared__ float hist_s[MT * T_ENC * DIN];                 // 6.4 KB
    __shared__ float pred_buf[MT * T_DEC * DIN];               // 7.7 KB
    __shared__ __align__(16) float2 part_s[8][MT];             // 1 KB
    __shared__ float wemb_s[EMB * DIN];
    __shared__ float bemb_s[EMB];

    const int tid = threadIdx.x;
    const int L   = tid & 63;
    const int w   = tid >> 6;       // wave 0..7
    const int nc  = L & 15;
    const int kb0 = (L >> 4) * 8;   // A-frag k base
    const int m0c = (L >> 4) * 4;   // C-frag row base
    const int r0  = blockIdx.x * MT;
    const int jcol = w * 16 + nc;   // owned hidden unit / gate sub-column

    // ---- staging ----
    for (int i = tid; i < MT * T_ENC * DIN; i += NTHR)
        hist_s[i] = history[r0 * T_ENC * DIN + i];
    for (int i = tid; i < MT * HS; i += NTHR) {
        hhi[0][i] = 0; hlo[0][i] = 0;
        hhi[1][i] = 0; hlo[1][i] = 0;
    }
    if (tid < EMB * DIN) wemb_s[tid] = W_emb[tid];
    if (tid < EMB) bemb_s[tid] = b_emb[tid];

    // ---- persistent weight fragments (gate-fused: tile g covers n = g*128 + jcol) ----
    // sched_barrier(0) after each group: caps instantaneous register pressure so
    // the 40 conversions don't cluster into a one-time scratch-spill burst
    // (R9 evidence: WRITE_SIZE 38 MB vs 2 MB output, FETCH only 15 MB).
    frag8 Bg[4][4][2];   // 128 VGPRs
#pragma unroll
    for (int g = 0; g < 4; ++g) {
#pragma unroll
        for (int ks = 0; ks < 4; ++ks) {
            int n = g * HID + jcol;
            load_wfrag(&W_hh[(size_t)n * HID + ks * 32 + kb0], Bg[g][ks][0], Bg[g][ks][1]);
        }
        __builtin_amdgcn_sched_barrier(0);
    }
    frag8 Bw1[4][2];     // 32 VGPRs; wave owns u-tile w*16..+15
#pragma unroll
    for (int ks = 0; ks < 4; ++ks)
        load_wfrag(&W1[(size_t)jcol * HID + ks * 32 + kb0], Bw1[ks][0], Bw1[ks][1]);
    __builtin_amdgcn_sched_barrier(0);

    __syncthreads();   // staging visible

    // ---- folded rank-2 input map + biases for this lane's 4 gate columns ----
    float we0v[4], we1v[4], bs0v[4], bs1v[4];
#pragma unroll
    for (int g = 0; g < 4; ++g) {
        int n = g * HID + jcol;
        float s0 = 0.f, s1 = 0.f, sb = 0.f;
        const float* wr = &W_ih[(size_t)n * EMB];
#pragma unroll 4
        for (int e4 = 0; e4 < EMB / 4; ++e4) {
            float4 wv = *(const float4*)&wr[e4 * 4];
            int e = e4 * 4;
            s0 += wv.x * wemb_s[(e+0)*2] + wv.y * wemb_s[(e+1)*2]
                + wv.z * wemb_s[(e+2)*2] + wv.w * wemb_s[(e+3)*2];
            s1 += wv.x * wemb_s[(e+0)*2+1] + wv.y * wemb_s[(e+1)*2+1]
                + wv.z * wemb_s[(e+2)*2+1] + wv.w * wemb_s[(e+3)*2+1];
            sb += wv.x * bemb_s[e+0] + wv.y * bemb_s[e+1]
                + wv.z * bemb_s[e+2] + wv.w * bemb_s[e+3];
        }
        float b = b_ih[n] + b_hh[n];
        bs0v[g] = b;          // decoder step 0: prev is literal zeros
        bs1v[g] = b + sb;     // input went through embedding
        we0v[g] = s0; we1v[g] = s1;
    }
    const float b1v  = b1[jcol];
    const float w2v0 = w2[jcol];          // W2[0][u]
    const float w2v1 = w2[HID + jcol];    // W2[1][u]
    const float b2v0 = b2[0], b2v1 = b2[1];
    const int   fb   = nc * HS + kb0;     // A-frag base (shorts)
    float cst[4] = {0.f, 0.f, 0.f, 0.f};  // c state: rows m0c+r, unit jcol

    const unsigned short* Hh = hhi[0];
    const unsigned short* Hl = hlo[0];
    unsigned short* Nh = hhi[1];
    unsigned short* Nl = hlo[1];

    // =================== encoder: ONE barrier per step (dbuf) ===================
#pragma unroll 1
    for (int t = 0; t < T_ENC; ++t) {
        // issue first A-frag reads early (latency overlaps acc-init VALU)
        frag8 Ahi0 = *(const frag8*)(Hh + fb);
        frag8 Alo0 = *(const frag8*)(Hl + fb);

        f32x4 acc[4];
        float q0[4], q1[4];
#pragma unroll
        for (int r = 0; r < 4; ++r) {
            float2 q = *(const float2*)&hist_s[(m0c + r) * (T_ENC * DIN) + t * DIN];
            q0[r] = q.x; q1[r] = q.y;
        }
#pragma unroll
        for (int g = 0; g < 4; ++g)
#pragma unroll
            for (int r = 0; r < 4; ++r)
                acc[g][r] = fmaf(q1[r], we1v[g], fmaf(q0[r], we0v[g], bs1v[g]));

#pragma unroll
        for (int ks = 0; ks < 4; ++ks) {
            frag8 Ahi = (ks == 0) ? Ahi0 : *(const frag8*)(Hh + fb + ks * 32);
            frag8 Alo = (ks == 0) ? Alo0 : *(const frag8*)(Hl + fb + ks * 32);
#pragma unroll
            for (int g = 0; g < 4; ++g)
                acc[g] = __builtin_amdgcn_mfma_f32_16x16x32_bf16(Ahi, Bg[g][ks][1], acc[g], 0, 0, 0);
#pragma unroll
            for (int g = 0; g < 4; ++g)
                acc[g] = __builtin_amdgcn_mfma_f32_16x16x32_bf16(Alo, Bg[g][ks][0], acc[g], 0, 0, 0);
#pragma unroll
            for (int g = 0; g < 4; ++g)
                acc[g] = __builtin_amdgcn_mfma_f32_16x16x32_bf16(Ahi, Bg[g][ks][0], acc[g], 0, 0, 0);
        }

#pragma unroll
        for (int r = 0; r < 4; ++r) {
            float i_ = sigm(acc[0][r]);
            float f_ = sigm(acc[1][r]);
            float gv = tanh_fast(acc[2][r]);
            float o_ = sigm(acc[3][r]);
            cst[r] = fmaf(f_, cst[r], i_ * gv);
            float h = o_ * tanh_fast(cst[r]);
            unsigned short phi, plo;
            split2(h, phi, plo);
            Nh[(m0c + r) * HS + jcol] = phi;
            Nl[(m0c + r) * HS + jcol] = plo;
        }
        // swap buffers
        { const unsigned short* th = Hh; Hh = Nh; Nh = (unsigned short*)th;
          const unsigned short* tl = Hl; Hl = Nl; Nl = (unsigned short*)tl; }
        __syncthreads();
    }

    // =================== decoder step 0 (peeled: prev = zeros, no pred yet) ===================
    {
        f32x4 acc[4];
#pragma unroll
        for (int g = 0; g < 4; ++g)
            acc[g] = (f32x4){bs0v[g], bs0v[g], bs0v[g], bs0v[g]};
#pragma unroll
        for (int ks = 0; ks < 4; ++ks) {
            frag8 Ahi = *(const frag8*)(Hh + fb + ks * 32);
            frag8 Alo = *(const frag8*)(Hl + fb + ks * 32);
#pragma unroll
            for (int g = 0; g < 4; ++g)
                acc[g] = __builtin_amdgcn_mfma_f32_16x16x32_bf16(Ahi, Bg[g][ks][1], acc[g], 0, 0, 0);
#pragma unroll
            for (int g = 0; g < 4; ++g)
                acc[g] = __builtin_amdgcn_mfma_f32_16x16x32_bf16(Alo, Bg[g][ks][0], acc[g], 0, 0, 0);
#pragma unroll
            for (int g = 0; g < 4; ++g)
                acc[g] = __builtin_amdgcn_mfma_f32_16x16x32_bf16(Ahi, Bg[g][ks][0], acc[g], 0, 0, 0);
        }
#pragma unroll
        for (int r = 0; r < 4; ++r) {
            float i_ = sigm(acc[0][r]);
            float f_ = sigm(acc[1][r]);
            float gv = tanh_fast(acc[2][r]);
            float o_ = sigm(acc[3][r]);
            cst[r] = fmaf(f_, cst[r], i_ * gv);
            float h = o_ * tanh_fast(cst[r]);
            unsigned short phi, plo;
            split2(h, phi, plo);
            Nh[(m0c + r) * HS + jcol] = phi;
            Nl[(m0c + r) * HS + jcol] = plo;
        }
        { const unsigned short* th = Hh; Hh = Nh; Nh = (unsigned short*)th;
          const unsigned short* tl = Hl; Hl = Nl; Nl = (unsigned short*)tl; }
        __syncthreads();
    }

    // =================== decoder steps 1..59: fused burst, TWO barriers/step ===================
#pragma unroll 1
    for (int it = 1; it < T_DEC; ++it) {
        frag8 Ahi0 = *(const frag8*)(Hh + fb);
        frag8 Alo0 = *(const frag8*)(Hl + fb);

        f32x4 acc[4];
        f32x4 hacc = (f32x4){b1v, b1v, b1v, b1v};
#pragma unroll
        for (int g = 0; g < 4; ++g)
            acc[g] = (f32x4){bs1v[g], bs1v[g], bs1v[g], bs1v[g]};

        // fused 60-MFMA burst: gates(h_{it-1}) + hid_{it-1}, 5 independent chains
#pragma unroll
        for (int ks = 0; ks < 4; ++ks) {
            frag8 Ahi = (ks == 0) ? Ahi0 : *(const frag8*)(Hh + fb + ks * 32);
            frag8 Alo = (ks == 0) ? Alo0 : *(const frag8*)(Hl + fb + ks * 32);
#pragma unroll
            for (int g = 0; g < 4; ++g)
                acc[g] = __builtin_amdgcn_mfma_f32_16x16x32_bf16(Ahi, Bg[g][ks][1], acc[g], 0, 0, 0);
            hacc = __builtin_amdgcn_mfma_f32_16x16x32_bf16(Ahi, Bw1[ks][1], hacc, 0, 0, 0);
#pragma unroll
            for (int g = 0; g < 4; ++g)
                acc[g] = __builtin_amdgcn_mfma_f32_16x16x32_bf16(Alo, Bg[g][ks][0], acc[g], 0, 0, 0);
            hacc = __builtin_amdgcn_mfma_f32_16x16x32_bf16(Alo, Bw1[ks][0], hacc, 0, 0, 0);
#pragma unroll
            for (int g = 0; g < 4; ++g)
                acc[g] = __builtin_amdgcn_mfma_f32_16x16x32_bf16(Ahi, Bg[g][ks][0], acc[g], 0, 0, 0);
            hacc = __builtin_amdgcn_mfma_f32_16x16x32_bf16(Ahi, Bw1[ks][0], hacc, 0, 0, 0);
        }

        // hid=relu -> per-lane pred partials -> 16-lane shfl reduce
        float p0[4], p1[4];
#pragma unroll
        for (int r = 0; r < 4; ++r) {
            float hv = fmaxf(hacc[r], 0.f);
            p0[r] = hv * w2v0;
            p1[r] = hv * w2v1;
        }
#pragma unroll
        for (int mask = 1; mask < 16; mask <<= 1)
#pragma unroll
            for (int r = 0; r < 4; ++r) {
                p0[r] += __shfl_xor(p0[r], mask);
                p1[r] += __shfl_xor(p1[r], mask);
            }
        if (nc == 0)
#pragma unroll
            for (int r = 0; r < 4; ++r)
                part_s[w][m0c + r] = (float2){p0[r], p1[r]};
        __syncthreads();   // partials visible (barrier 1)

        // every lane computes pred for its 4 rows locally (broadcast b128 reads)
        float pr0[4] = {b2v0, b2v0, b2v0, b2v0};
        float pr1[4] = {b2v1, b2v1, b2v1, b2v1};
#pragma unroll
        for (int wi = 0; wi < 8; ++wi) {
            f32x4 va = *(const f32x4*)&part_s[wi][m0c];       // rows m0c, m0c+1
            f32x4 vb = *(const f32x4*)&part_s[wi][m0c + 2];   // rows m0c+2, m0c+3
            pr0[0] += va.x; pr1[0] += va.y;
            pr0[1] += va.z; pr1[1] += va.w;
            pr0[2] += vb.x; pr1[2] += vb.y;
            pr0[3] += vb.z; pr1[3] += vb.w;
        }
        // designated lanes write pred_{it-1} to the output staging buffer
        if (w == 0 && nc == 0)
#pragma unroll
            for (int r = 0; r < 4; ++r)
                *(float2*)&pred_buf[((m0c + r) * T_DEC + (it - 1)) * DIN] =
                    (float2){pr0[r], pr1[r]};

        // rank-2 input term from in-register preds
#pragma unroll
        for (int g = 0; g < 4; ++g)
#pragma unroll
            for (int r = 0; r < 4; ++r)
                acc[g][r] += fmaf(pr1[r], we1v[g], pr0[r] * we0v[g]);

        // pointwise -> h_it
#pragma unroll
        for (int r = 0; r < 4; ++r) {
            float i_ = sigm(acc[0][r]);
            float f_ = sigm(acc[1][r]);
            float gv = tanh_fast(acc[2][r]);
            float o_ = sigm(acc[3][r]);
            cst[r] = fmaf(f_, cst[r], i_ * gv);
            float h = o_ * tanh_fast(cst[r]);
            unsigned short phi, plo;
            split2(h, phi, plo);
            Nh[(m0c + r) * HS + jcol] = phi;
            Nl[(m0c + r) * HS + jcol] = plo;
        }
        { const unsigned short* th = Hh; Hh = Nh; Nh = (unsigned short*)th;
          const unsigned short* tl = Hl; Hl = Nl; Nl = (unsigned short*)tl; }
        __syncthreads();   // new h visible (barrier 2)
    }

    // =================== tail: pred of the last decoder state ===================
    {
        f32x4 hacc = (f32x4){b1v, b1v, b1v, b1v};
#pragma unroll
        for (int ks = 0; ks < 4; ++ks) {
            frag8 Ahi = *(const frag8*)(Hh + fb + ks * 32);
            frag8 Alo = *(const frag8*)(Hl + fb + ks * 32);
            hacc = __builtin_amdgcn_mfma_f32_16x16x32_bf16(Ahi, Bw1[ks][1], hacc, 0, 0, 0);
            hacc = __builtin_amdgcn_mfma_f32_16x16x32_bf16(Alo, Bw1[ks][0], hacc, 0, 0, 0);
            hacc = __builtin_amdgcn_mfma_f32_16x16x32_bf16(Ahi, Bw1[ks][0], hacc, 0, 0, 0);
        }
        float p0[4], p1[4];
#pragma unroll
        for (int r = 0; r < 4; ++r) {
            float hv = fmaxf(hacc[r], 0.f);
            p0[r] = hv * w2v0;
            p1[r] = hv * w2v1;
        }
#pragma unroll
        for (int mask = 1; mask < 16; mask <<= 1)
#pragma unroll
            for (int r = 0; r < 4; ++r) {
                p0[r] += __shfl_xor(p0[r], mask);
                p1[r] += __shfl_xor(p1[r], mask);
            }
        if (nc == 0)
#pragma unroll
            for (int r = 0; r < 4; ++r)
                part_s[w][m0c + r] = (float2){p0[r], p1[r]};
        __syncthreads();
        if (w == 0 && nc == 0) {
            float pr0[4] = {b2v0, b2v0, b2v0, b2v0};
            float pr1[4] = {b2v1, b2v1, b2v1, b2v1};
#pragma unroll
            for (int wi = 0; wi < 8; ++wi) {
                f32x4 va = *(const f32x4*)&part_s[wi][m0c];
                f32x4 vb = *(const f32x4*)&part_s[wi][m0c + 2];
                pr0[0] += va.x; pr1[0] += va.y;
                pr0[1] += va.z; pr1[1] += va.w;
                pr0[2] += vb.x; pr1[2] += vb.y;
                pr0[3] += vb.z; pr1[3] += vb.w;
            }
#pragma unroll
            for (int r = 0; r < 4; ++r)
                *(float2*)&pred_buf[((m0c + r) * T_DEC + (T_DEC - 1)) * DIN] =
                    (float2){pr0[r], pr1[r]};
        }
        __syncthreads();
    }

    // ---- single coalesced flush of all preds ----
    for (int i = tid; i < MT * T_DEC * DIN; i += NTHR)
        out[(size_t)r0 * T_DEC * DIN + i] = pred_buf[i];
}

extern "C" void kernel_launch(void* const* d_in, const int* in_sizes, int n_in,
                              void* d_out, int out_size, void* d_ws, size_t ws_size,
                              hipStream_t stream) {
    const float* history = (const float*)d_in[0];
    const float* W_emb   = (const float*)d_in[1];
    const float* b_emb   = (const float*)d_in[2];
    const float* W_ih    = (const float*)d_in[3];
    const float* W_hh    = (const float*)d_in[4];
    const float* b_ih    = (const float*)d_in[5];
    const float* b_hh    = (const float*)d_in[6];
    const float* W1      = (const float*)d_in[7];
    const float* b1      = (const float*)d_in[8];
    const float* W2      = (const float*)d_in[9];
    const float* b2      = (const float*)d_in[10];
    float* out = (float*)d_out;
    (void)d_ws; (void)ws_size; (void)in_sizes; (void)n_in; (void)out_size;

    lstm_all<<<4096 / MT, NTHR, 0, stream>>>(history, W_emb, b_emb, W_ih, W_hh,
                                             b_ih, b_hh, W1, b1, W2, b2, out);
}

// Round 11
// 328.838 us; speedup vs baseline: 1.1859x; 1.1859x over previous
//
#include <hip/hip_runtime.h>
#include <math.h>

// Problem constants
#define T_ENC 50
#define T_DEC 60
#define HID   128
#define EMB   64
#define DIN   2
#define MT    16      // batch rows per block
#define NTHR  512     // 8 waves, 1 block/CU -> 2 waves/SIMD
#define HS    136     // shorts per h row (16B-aligned rows; pad breaks pow2 stride)

typedef __attribute__((ext_vector_type(8))) short frag8;  // 8 bf16 (4 VGPRs)
typedef __attribute__((ext_vector_type(4))) float f32x4;  // 4 fp32 acc

__device__ __forceinline__ float fast_rcp(float x) { return __builtin_amdgcn_rcpf(x); }
__device__ __forceinline__ float sigm(float x) { return fast_rcp(1.f + __expf(-x)); }
__device__ __forceinline__ float tanh_fast(float x) { return fmaf(2.f, fast_rcp(1.f + __expf(-2.f * x)), -1.f); }

// Split 8 consecutive floats W[n][kb..kb+7] into hi/lo bf16 fragment registers.
__device__ __forceinline__ void load_wfrag(const float* __restrict__ wrow,
                                           frag8& Fhi, frag8& Flo) {
    union { unsigned short s[8]; frag8 f; } hi, lo;
#pragma unroll
    for (int j = 0; j < 8; ++j) {
        float x      = wrow[j];
        unsigned u   = __float_as_uint(x);
        unsigned uhi = u & 0xffff0000u;
        float    lof = x - __uint_as_float(uhi);   // exact remainder
        hi.s[j] = (unsigned short)(uhi >> 16);
        lo.s[j] = (unsigned short)(__float_as_uint(lof) >> 16);
    }
    Fhi = hi.f; Flo = lo.f;
}

__device__ __forceinline__ void split2(float x, unsigned short& hi, unsigned short& lo) {
    unsigned u   = __float_as_uint(x);
    unsigned uhi = u & 0xffff0000u;
    float    lof = x - __uint_as_float(uhi);
    hi = (unsigned short)(uhi >> 16);
    lo = (unsigned short)(__float_as_uint(lof) >> 16);
}

// R10 lesson: the hot loop sits exactly at the 128-VGPR cliff — any change
// adding >~8 live VGPRs in the loop causes per-step spill (FETCH +5 MB, -15%).
// All R11 additions are register-neutral (scalar s + immediate shfl consume).
__global__ __launch_bounds__(NTHR, 2) void lstm_all(
    const float* __restrict__ history,  // (B, 50, 2)
    const float* __restrict__ W_emb,    // (64, 2)
    const float* __restrict__ b_emb,    // (64)
    const float* __restrict__ W_ih,     // (512, 64)
    const float* __restrict__ W_hh,     // (512, 128)
    const float* __restrict__ b_ih,     // (512)
    const float* __restrict__ b_hh,     // (512)
    const float* __restrict__ W1,       // (128, 128)
    const float* __restrict__ b1,       // (128)
    const float* __restrict__ w2,       // (2, 128)
    const float* __restrict__ b2,       // (2)
    float* __restrict__ out)            // (B, 60, 2)
{
    __shared__ __align__(16) unsigned short hhi[2][MT * HS];   // 8.7 KB
    __shared__ __align__(16) unsigned short hlo[2][MT * HS];   // 8.7 KB
    __shared__ float hist_s[MT * T_ENC * DIN];                 // 6.4 KB
    __shared__ float pred_buf[MT * T_DEC * DIN];               // 7.7 KB
    __shared__ __align__(16) float2 part_s[8][MT];             // 1 KB
    __shared__ float wemb_s[EMB * DIN];
    __shared__ float bemb_s[EMB];

    const int tid = threadIdx.x;
    const int L   = tid & 63;
    const int w   = tid >> 6;       // wave 0..7
    const int nc  = L & 15;
    const int kb0 = (L >> 4) * 8;   // A-frag k base
    const int m0c = (L >> 4) * 4;   // C-frag row base
    const int r0  = blockIdx.x * MT;
    const int jcol = w * 16 + nc;   // owned hidden unit / gate sub-column

    // ---- staging ----
    for (int i = tid; i < MT * T_ENC * DIN; i += NTHR)
        hist_s[i] = history[r0 * T_ENC * DIN + i];
    for (int i = tid; i < MT * HS; i += NTHR) {
        hhi[0][i] = 0; hlo[0][i] = 0;
        hhi[1][i] = 0; hlo[1][i] = 0;
    }
    if (tid < EMB * DIN) wemb_s[tid] = W_emb[tid];
    if (tid < EMB) bemb_s[tid] = b_emb[tid];

    // ---- persistent weight fragments (gate-fused: tile g covers n = g*128 + jcol) ----
    // __syncthreads() between groups: hard fence the compiler cannot hoist the
    // 160 global loads across -> caps landing-buffer pressure (the one-time
    // setup scratch burst seen as WRITE_SIZE ~38 MB). sched_barrier didn't work (R10).
    frag8 Bg[4][4][2];   // 128 VGPRs
#pragma unroll
    for (int g = 0; g < 4; ++g) {
#pragma unroll
        for (int ks = 0; ks < 4; ++ks) {
            int n = g * HID + jcol;
            load_wfrag(&W_hh[(size_t)n * HID + ks * 32 + kb0], Bg[g][ks][0], Bg[g][ks][1]);
        }
        __syncthreads();
    }
    frag8 Bw1[4][2];     // 32 VGPRs; wave owns u-tile w*16..+15
#pragma unroll
    for (int ks = 0; ks < 4; ++ks)
        load_wfrag(&W1[(size_t)jcol * HID + ks * 32 + kb0], Bw1[ks][0], Bw1[ks][1]);

    __syncthreads();   // staging visible

    // ---- folded rank-2 input map + biases for this lane's 4 gate columns ----
    float we0v[4], we1v[4], bs0v[4], bs1v[4];
#pragma unroll
    for (int g = 0; g < 4; ++g) {
        int n = g * HID + jcol;
        float s0 = 0.f, s1 = 0.f, sb = 0.f;
        const float* wr = &W_ih[(size_t)n * EMB];
#pragma unroll 4
        for (int e4 = 0; e4 < EMB / 4; ++e4) {
            float4 wv = *(const float4*)&wr[e4 * 4];
            int e = e4 * 4;
            s0 += wv.x * wemb_s[(e+0)*2] + wv.y * wemb_s[(e+1)*2]
                + wv.z * wemb_s[(e+2)*2] + wv.w * wemb_s[(e+3)*2];
            s1 += wv.x * wemb_s[(e+0)*2+1] + wv.y * wemb_s[(e+1)*2+1]
                + wv.z * wemb_s[(e+2)*2+1] + wv.w * wemb_s[(e+3)*2+1];
            sb += wv.x * bemb_s[e+0] + wv.y * bemb_s[e+1]
                + wv.z * bemb_s[e+2] + wv.w * bemb_s[e+3];
        }
        float b = b_ih[n] + b_hh[n];
        bs0v[g] = b;          // decoder step 0: prev is literal zeros
        bs1v[g] = b + sb;     // input went through embedding
        we0v[g] = s0; we1v[g] = s1;
    }
    const float b1v  = b1[jcol];
    const float w2v0 = w2[jcol];          // W2[0][u]
    const float w2v1 = w2[HID + jcol];    // W2[1][u]
    const float b2v0 = b2[0], b2v1 = b2[1];
    const int   fb   = nc * HS + kb0;     // A-frag base (shorts)
    float cst[4] = {0.f, 0.f, 0.f, 0.f};  // c state: rows m0c+r, unit jcol

    const unsigned short* Hh = hhi[0];
    const unsigned short* Hl = hlo[0];
    unsigned short* Nh = hhi[1];
    unsigned short* Nl = hlo[1];

    // =================== encoder: ONE barrier per step (dbuf) ===================
#pragma unroll 1
    for (int t = 0; t < T_ENC; ++t) {
        f32x4 acc[4];
        float q0[4], q1[4];
#pragma unroll
        for (int r = 0; r < 4; ++r) {
            float2 q = *(const float2*)&hist_s[(m0c + r) * (T_ENC * DIN) + t * DIN];
            q0[r] = q.x; q1[r] = q.y;
        }
#pragma unroll
        for (int g = 0; g < 4; ++g)
#pragma unroll
            for (int r = 0; r < 4; ++r)
                acc[g][r] = fmaf(q1[r], we1v[g], fmaf(q0[r], we0v[g], bs1v[g]));

#pragma unroll
        for (int ks = 0; ks < 4; ++ks) {
            frag8 Ahi = *(const frag8*)(Hh + fb + ks * 32);
            frag8 Alo = *(const frag8*)(Hl + fb + ks * 32);
#pragma unroll
            for (int g = 0; g < 4; ++g)
                acc[g] = __builtin_amdgcn_mfma_f32_16x16x32_bf16(Ahi, Bg[g][ks][1], acc[g], 0, 0, 0);
#pragma unroll
            for (int g = 0; g < 4; ++g)
                acc[g] = __builtin_amdgcn_mfma_f32_16x16x32_bf16(Alo, Bg[g][ks][0], acc[g], 0, 0, 0);
#pragma unroll
            for (int g = 0; g < 4; ++g)
                acc[g] = __builtin_amdgcn_mfma_f32_16x16x32_bf16(Ahi, Bg[g][ks][0], acc[g], 0, 0, 0);
        }

#pragma unroll
        for (int r = 0; r < 4; ++r) {
            float i_ = sigm(acc[0][r]);
            float f_ = sigm(acc[1][r]);
            float gv = tanh_fast(acc[2][r]);
            float o_ = sigm(acc[3][r]);
            cst[r] = fmaf(f_, cst[r], i_ * gv);
            float h = o_ * tanh_fast(cst[r]);
            unsigned short phi, plo;
            split2(h, phi, plo);
            Nh[(m0c + r) * HS + jcol] = phi;
            Nl[(m0c + r) * HS + jcol] = plo;
        }
        { const unsigned short* th = Hh; Hh = Nh; Nh = (unsigned short*)th;
          const unsigned short* tl = Hl; Hl = Nl; Nl = (unsigned short*)tl; }
        __syncthreads();
    }

    // =================== decoder step 0 (peeled: prev = zeros) ===================
    {
        f32x4 acc[4];
#pragma unroll
        for (int g = 0; g < 4; ++g)
            acc[g] = (f32x4){bs0v[g], bs0v[g], bs0v[g], bs0v[g]};
#pragma unroll
        for (int ks = 0; ks < 4; ++ks) {
            frag8 Ahi = *(const frag8*)(Hh + fb + ks * 32);
            frag8 Alo = *(const frag8*)(Hl + fb + ks * 32);
#pragma unroll
            for (int g = 0; g < 4; ++g)
                acc[g] = __builtin_amdgcn_mfma_f32_16x16x32_bf16(Ahi, Bg[g][ks][1], acc[g], 0, 0, 0);
#pragma unroll
            for (int g = 0; g < 4; ++g)
                acc[g] = __builtin_amdgcn_mfma_f32_16x16x32_bf16(Alo, Bg[g][ks][0], acc[g], 0, 0, 0);
#pragma unroll
            for (int g = 0; g < 4; ++g)
                acc[g] = __builtin_amdgcn_mfma_f32_16x16x32_bf16(Ahi, Bg[g][ks][0], acc[g], 0, 0, 0);
        }
#pragma unroll
        for (int r = 0; r < 4; ++r) {
            float i_ = sigm(acc[0][r]);
            float f_ = sigm(acc[1][r]);
            float gv = tanh_fast(acc[2][r]);
            float o_ = sigm(acc[3][r]);
            cst[r] = fmaf(f_, cst[r], i_ * gv);
            float h = o_ * tanh_fast(cst[r]);
            unsigned short phi, plo;
            split2(h, phi, plo);
            Nh[(m0c + r) * HS + jcol] = phi;
            Nl[(m0c + r) * HS + jcol] = plo;
        }
        { const unsigned short* th = Hh; Hh = Nh; Nh = (unsigned short*)th;
          const unsigned short* tl = Hl; Hl = Nl; Nl = (unsigned short*)tl; }
        __syncthreads();
    }

    // =================== decoder steps 1..59: fused burst, TWO barriers/step ===================
#pragma unroll 1
    for (int it = 1; it < T_DEC; ++it) {
        f32x4 acc[4];
        f32x4 hacc = (f32x4){b1v, b1v, b1v, b1v};
#pragma unroll
        for (int g = 0; g < 4; ++g)
            acc[g] = (f32x4){bs1v[g], bs1v[g], bs1v[g], bs1v[g]};

        // fused 60-MFMA burst: gates(h_{it-1}) + hid_{it-1}, 5 independent chains
#pragma unroll
        for (int ks = 0; ks < 4; ++ks) {
            frag8 Ahi = *(const frag8*)(Hh + fb + ks * 32);
            frag8 Alo = *(const frag8*)(Hl + fb + ks * 32);
#pragma unroll
            for (int g = 0; g < 4; ++g)
                acc[g] = __builtin_amdgcn_mfma_f32_16x16x32_bf16(Ahi, Bg[g][ks][1], acc[g], 0, 0, 0);
            hacc = __builtin_amdgcn_mfma_f32_16x16x32_bf16(Ahi, Bw1[ks][1], hacc, 0, 0, 0);
#pragma unroll
            for (int g = 0; g < 4; ++g)
                acc[g] = __builtin_amdgcn_mfma_f32_16x16x32_bf16(Alo, Bg[g][ks][0], acc[g], 0, 0, 0);
            hacc = __builtin_amdgcn_mfma_f32_16x16x32_bf16(Alo, Bw1[ks][0], hacc, 0, 0, 0);
#pragma unroll
            for (int g = 0; g < 4; ++g)
                acc[g] = __builtin_amdgcn_mfma_f32_16x16x32_bf16(Ahi, Bg[g][ks][0], acc[g], 0, 0, 0);
            hacc = __builtin_amdgcn_mfma_f32_16x16x32_bf16(Ahi, Bw1[ks][0], hacc, 0, 0, 0);
        }

        // hid=relu -> per-lane pred partials -> 16-lane shfl reduce
        float p0[4], p1[4];
#pragma unroll
        for (int r = 0; r < 4; ++r) {
            float hv = fmaxf(hacc[r], 0.f);
            p0[r] = hv * w2v0;
            p1[r] = hv * w2v1;
        }
#pragma unroll
        for (int mask = 1; mask < 16; mask <<= 1)
#pragma unroll
            for (int r = 0; r < 4; ++r) {
                p0[r] += __shfl_xor(p0[r], mask);
                p1[r] += __shfl_xor(p1[r], mask);
            }
        if (nc == 0)
#pragma unroll
            for (int r = 0; r < 4; ++r)
                part_s[w][m0c + r] = (float2){p0[r], p1[r]};
        __syncthreads();   // partials visible (barrier 1)

        // Every wave recomputes all 32 preds redundantly (register-neutral:
        // one scalar, broadcast LDS reads), then shfl-broadcasts into lanes.
        {
            const int mm = (L >> 1) & 15;
            const int dd = L & 1;
            float s = dd ? b2v1 : b2v0;
#pragma unroll
            for (int wi = 0; wi < 8; ++wi)
                s += ((const float*)&part_s[wi][mm])[dd];
            if (w == 0 && L < 32)
                pred_buf[(mm * T_DEC + (it - 1)) * DIN + dd] = s;   // read only at final flush
#pragma unroll
            for (int r = 0; r < 4; ++r) {
                float pq0 = __shfl(s, (m0c + r) * 2);
                float pq1 = __shfl(s, (m0c + r) * 2 + 1);
#pragma unroll
                for (int g = 0; g < 4; ++g)
                    acc[g][r] += fmaf(pq1, we1v[g], pq0 * we0v[g]);
            }
        }

        // pointwise -> h_it
#pragma unroll
        for (int r = 0; r < 4; ++r) {
            float i_ = sigm(acc[0][r]);
            float f_ = sigm(acc[1][r]);
            float gv = tanh_fast(acc[2][r]);
            float o_ = sigm(acc[3][r]);
            cst[r] = fmaf(f_, cst[r], i_ * gv);
            float h = o_ * tanh_fast(cst[r]);
            unsigned short phi, plo;
            split2(h, phi, plo);
            Nh[(m0c + r) * HS + jcol] = phi;
            Nl[(m0c + r) * HS + jcol] = plo;
        }
        { const unsigned short* th = Hh; Hh = Nh; Nh = (unsigned short*)th;
          const unsigned short* tl = Hl; Hl = Nl; Nl = (unsigned short*)tl; }
        __syncthreads();   // new h visible (barrier 2)
    }

    // =================== tail: pred of the last decoder state ===================
    {
        f32x4 hacc = (f32x4){b1v, b1v, b1v, b1v};
#pragma unroll
        for (int ks = 0; ks < 4; ++ks) {
            frag8 Ahi = *(const frag8*)(Hh + fb + ks * 32);
            frag8 Alo = *(const frag8*)(Hl + fb + ks * 32);
            hacc = __builtin_amdgcn_mfma_f32_16x16x32_bf16(Ahi, Bw1[ks][1], hacc, 0, 0, 0);
            hacc = __builtin_amdgcn_mfma_f32_16x16x32_bf16(Alo, Bw1[ks][0], hacc, 0, 0, 0);
            hacc = __builtin_amdgcn_mfma_f32_16x16x32_bf16(Ahi, Bw1[ks][0], hacc, 0, 0, 0);
        }
        float p0[4], p1[4];
#pragma unroll
        for (int r = 0; r < 4; ++r) {
            float hv = fmaxf(hacc[r], 0.f);
            p0[r] = hv * w2v0;
            p1[r] = hv * w2v1;
        }
#pragma unroll
        for (int mask = 1; mask < 16; mask <<= 1)
#pragma unroll
            for (int r = 0; r < 4; ++r) {
                p0[r] += __shfl_xor(p0[r], mask);
                p1[r] += __shfl_xor(p1[r], mask);
            }
        if (nc == 0)
#pragma unroll
            for (int r = 0; r < 4; ++r)
                part_s[w][m0c + r] = (float2){p0[r], p1[r]};
        __syncthreads();
        if (w == 0 && L < 32) {
            const int mm = L >> 1;
            const int dd = L & 1;
            float s = dd ? b2v1 : b2v0;
#pragma unroll
            for (int wi = 0; wi < 8; ++wi)
                s += ((const float*)&part_s[wi][mm])[dd];
            pred_buf[(mm * T_DEC + (T_DEC - 1)) * DIN + dd] = s;
        }
        __syncthreads();
    }

    // ---- single coalesced flush of all preds ----
    for (int i = tid; i < MT * T_DEC * DIN; i += NTHR)
        out[(size_t)r0 * T_DEC * DIN + i] = pred_buf[i];
}

extern "C" void kernel_launch(void* const* d_in, const int* in_sizes, int n_in,
                              void* d_out, int out_size, void* d_ws, size_t ws_size,
                              hipStream_t stream) {
    const float* history = (const float*)d_in[0];
    const float* W_emb   = (const float*)d_in[1];
    const float* b_emb   = (const float*)d_in[2];
    const float* W_ih    = (const float*)d_in[3];
    const float* W_hh    = (const float*)d_in[4];
    const float* b_ih    = (const float*)d_in[5];
    const float* b_hh    = (const float*)d_in[6];
    const float* W1      = (const float*)d_in[7];
    const float* b1      = (const float*)d_in[8];
    const float* W2      = (const float*)d_in[9];
    const float* b2      = (const float*)d_in[10];
    float* out = (float*)d_out;
    (void)d_ws; (void)ws_size; (void)in_sizes; (void)n_in; (void)out_size;

    lstm_all<<<4096 / MT, NTHR, 0, stream>>>(history, W_emb, b_emb, W_ih, W_hh,
                                             b_ih, b_hh, W1, b1, W2, b2, out);
}

// Round 12
// 323.538 us; speedup vs baseline: 1.2053x; 1.0164x over previous
//
#include <hip/hip_runtime.h>
#include <math.h>

// Problem constants
#define T_ENC 50
#define T_DEC 60
#define HID   128
#define EMB   64
#define DIN   2
#define MT    16      // batch rows per block
#define NTHR  512     // 8 waves, 1 block/CU -> 2 waves/SIMD
#define HS    136     // shorts per h row (16B-aligned rows; pad breaks pow2 stride)

typedef __attribute__((ext_vector_type(8))) short frag8;  // 8 bf16 (4 VGPRs)
typedef __attribute__((ext_vector_type(4))) float f32x4;  // 4 fp32 acc

__device__ __forceinline__ float fast_rcp(float x) { return __builtin_amdgcn_rcpf(x); }
__device__ __forceinline__ float sigm(float x) { return fast_rcp(1.f + __expf(-x)); }
__device__ __forceinline__ float tanh_fast(float x) { return fmaf(2.f, fast_rcp(1.f + __expf(-2.f * x)), -1.f); }

// Split 8 consecutive floats W[n][kb..kb+7] into hi/lo bf16 fragment registers.
__device__ __forceinline__ void load_wfrag(const float* __restrict__ wrow,
                                           frag8& Fhi, frag8& Flo) {
    union { unsigned short s[8]; frag8 f; } hi, lo;
#pragma unroll
    for (int j = 0; j < 8; ++j) {
        float x      = wrow[j];
        unsigned u   = __float_as_uint(x);
        unsigned uhi = u & 0xffff0000u;
        float    lof = x - __uint_as_float(uhi);   // exact remainder
        hi.s[j] = (unsigned short)(uhi >> 16);
        lo.s[j] = (unsigned short)(__float_as_uint(lof) >> 16);
    }
    Fhi = hi.f; Flo = lo.f;
}

__device__ __forceinline__ void split2(float x, unsigned short& hi, unsigned short& lo) {
    unsigned u   = __float_as_uint(x);
    unsigned uhi = u & 0xffff0000u;
    float    lof = x - __uint_as_float(uhi);
    hi = (unsigned short)(uhi >> 16);
    lo = (unsigned short)(__float_as_uint(lof) >> 16);
}

// Structure lock (R5-R11 evidence): W_hh split-bf16 = 256 KB fits neither LDS
// (160 KB) nor two register copies per CU -> exactly one weight-resident
// 8-wave block per CU; per-step all-wave barrier is required by the h
// cross-wave dependency; numerics locked at 3-term bf16 split (error
// amplification ~1600x kills every cheaper-precision variant).
__global__ __launch_bounds__(NTHR, 2) void lstm_all(
    const float* __restrict__ history,  // (B, 50, 2)
    const float* __restrict__ W_emb,    // (64, 2)
    const float* __restrict__ b_emb,    // (64)
    const float* __restrict__ W_ih,     // (512, 64)
    const float* __restrict__ W_hh,     // (512, 128)
    const float* __restrict__ b_ih,     // (512)
    const float* __restrict__ b_hh,     // (512)
    const float* __restrict__ W1,       // (128, 128)
    const float* __restrict__ b1,       // (128)
    const float* __restrict__ w2,       // (2, 128)
    const float* __restrict__ b2,       // (2)
    float* __restrict__ out)            // (B, 60, 2)
{
    __shared__ __align__(16) unsigned short hhi[2][MT * HS];   // 8.7 KB
    __shared__ __align__(16) unsigned short hlo[2][MT * HS];   // 8.7 KB
    __shared__ float hist_s[MT * T_ENC * DIN];                 // 6.4 KB
    __shared__ float pred_buf[MT * T_DEC * DIN];               // 7.7 KB
    __shared__ __align__(16) float2 part_s[8][MT];             // 1 KB
    __shared__ float wemb_s[EMB * DIN];
    __shared__ float bemb_s[EMB];

    const int tid = threadIdx.x;
    const int L   = tid & 63;
    const int w   = tid >> 6;       // wave 0..7
    const int nc  = L & 15;
    const int kb0 = (L >> 4) * 8;   // A-frag k base
    const int m0c = (L >> 4) * 4;   // C-frag row base
    const int r0  = blockIdx.x * MT;
    const int jcol = w * 16 + nc;   // owned hidden unit / gate sub-column

    // ---- staging ----
    for (int i = tid; i < MT * T_ENC * DIN; i += NTHR)
        hist_s[i] = history[r0 * T_ENC * DIN + i];
    for (int i = tid; i < MT * HS; i += NTHR) {
        hhi[0][i] = 0; hlo[0][i] = 0;
        hhi[1][i] = 0; hlo[1][i] = 0;
    }
    if (tid < EMB * DIN) wemb_s[tid] = W_emb[tid];
    if (tid < EMB) bemb_s[tid] = b_emb[tid];

    // ---- persistent weight fragments; __syncthreads() between groups caps
    //      landing-buffer pressure (R11: WRITE_SIZE 38 -> 14 MB) ----
    frag8 Bg[4][4][2];   // 128 VGPRs
#pragma unroll
    for (int g = 0; g < 4; ++g) {
#pragma unroll
        for (int ks = 0; ks < 4; ++ks) {
            int n = g * HID + jcol;
            load_wfrag(&W_hh[(size_t)n * HID + ks * 32 + kb0], Bg[g][ks][0], Bg[g][ks][1]);
        }
        __syncthreads();
    }
    frag8 Bw1[4][2];     // 32 VGPRs; wave owns u-tile w*16..+15
#pragma unroll
    for (int ks = 0; ks < 4; ++ks)
        load_wfrag(&W1[(size_t)jcol * HID + ks * 32 + kb0], Bw1[ks][0], Bw1[ks][1]);

    __syncthreads();   // staging visible

    // ---- folded rank-2 input map + biases for this lane's 4 gate columns ----
    float we0v[4], we1v[4], bs0v[4], bs1v[4];
#pragma unroll
    for (int g = 0; g < 4; ++g) {
        int n = g * HID + jcol;
        float s0 = 0.f, s1 = 0.f, sb = 0.f;
        const float* wr = &W_ih[(size_t)n * EMB];
#pragma unroll 4
        for (int e4 = 0; e4 < EMB / 4; ++e4) {
            float4 wv = *(const float4*)&wr[e4 * 4];
            int e = e4 * 4;
            s0 += wv.x * wemb_s[(e+0)*2] + wv.y * wemb_s[(e+1)*2]
                + wv.z * wemb_s[(e+2)*2] + wv.w * wemb_s[(e+3)*2];
            s1 += wv.x * wemb_s[(e+0)*2+1] + wv.y * wemb_s[(e+1)*2+1]
                + wv.z * wemb_s[(e+2)*2+1] + wv.w * wemb_s[(e+3)*2+1];
            sb += wv.x * bemb_s[e+0] + wv.y * bemb_s[e+1]
                + wv.z * bemb_s[e+2] + wv.w * bemb_s[e+3];
        }
        float b = b_ih[n] + b_hh[n];
        bs0v[g] = b;          // decoder step 0: prev is literal zeros
        bs1v[g] = b + sb;     // input went through embedding
        we0v[g] = s0; we1v[g] = s1;
    }
    const float b1v  = b1[jcol];
    const float w2v0 = w2[jcol];          // W2[0][u]
    const float w2v1 = w2[HID + jcol];    // W2[1][u]
    const float b2v0 = b2[0], b2v1 = b2[1];
    const int   fb   = nc * HS + kb0;     // A-frag base (shorts)
    float cst[4] = {0.f, 0.f, 0.f, 0.f};  // c state: rows m0c+r, unit jcol

    const unsigned short* Hh = hhi[0];
    const unsigned short* Hl = hlo[0];
    unsigned short* Nh = hhi[1];
    unsigned short* Nl = hlo[1];

    // =================== encoder: ONE barrier per step (dbuf) ===================
#pragma unroll 1
    for (int t = 0; t < T_ENC; ++t) {
        f32x4 acc[4];
        float q0[4], q1[4];
#pragma unroll
        for (int r = 0; r < 4; ++r) {
            float2 q = *(const float2*)&hist_s[(m0c + r) * (T_ENC * DIN) + t * DIN];
            q0[r] = q.x; q1[r] = q.y;
        }
#pragma unroll
        for (int g = 0; g < 4; ++g)
#pragma unroll
            for (int r = 0; r < 4; ++r)
                acc[g][r] = fmaf(q1[r], we1v[g], fmaf(q0[r], we0v[g], bs1v[g]));

#pragma unroll
        for (int ks = 0; ks < 4; ++ks) {
            frag8 Ahi = *(const frag8*)(Hh + fb + ks * 32);
            frag8 Alo = *(const frag8*)(Hl + fb + ks * 32);
#pragma unroll
            for (int g = 0; g < 4; ++g)
                acc[g] = __builtin_amdgcn_mfma_f32_16x16x32_bf16(Ahi, Bg[g][ks][1], acc[g], 0, 0, 0);
#pragma unroll
            for (int g = 0; g < 4; ++g)
                acc[g] = __builtin_amdgcn_mfma_f32_16x16x32_bf16(Alo, Bg[g][ks][0], acc[g], 0, 0, 0);
#pragma unroll
            for (int g = 0; g < 4; ++g)
                acc[g] = __builtin_amdgcn_mfma_f32_16x16x32_bf16(Ahi, Bg[g][ks][0], acc[g], 0, 0, 0);
        }

#pragma unroll
        for (int r = 0; r < 4; ++r) {
            float i_ = sigm(acc[0][r]);
            float f_ = sigm(acc[1][r]);
            float gv = tanh_fast(acc[2][r]);
            float o_ = sigm(acc[3][r]);
            cst[r] = fmaf(f_, cst[r], i_ * gv);
            float h = o_ * tanh_fast(cst[r]);
            unsigned short phi, plo;
            split2(h, phi, plo);
            Nh[(m0c + r) * HS + jcol] = phi;
            Nl[(m0c + r) * HS + jcol] = plo;
        }
        { const unsigned short* th = Hh; Hh = Nh; Nh = (unsigned short*)th;
          const unsigned short* tl = Hl; Hl = Nl; Nl = (unsigned short*)tl; }
        __syncthreads();
    }

    // =================== decoder step 0 (peeled: prev = zeros) ===================
    {
        f32x4 acc[4];
#pragma unroll
        for (int g = 0; g < 4; ++g)
            acc[g] = (f32x4){bs0v[g], bs0v[g], bs0v[g], bs0v[g]};
#pragma unroll
        for (int ks = 0; ks < 4; ++ks) {
            frag8 Ahi = *(const frag8*)(Hh + fb + ks * 32);
            frag8 Alo = *(const frag8*)(Hl + fb + ks * 32);
#pragma unroll
            for (int g = 0; g < 4; ++g)
                acc[g] = __builtin_amdgcn_mfma_f32_16x16x32_bf16(Ahi, Bg[g][ks][1], acc[g], 0, 0, 0);
#pragma unroll
            for (int g = 0; g < 4; ++g)
                acc[g] = __builtin_amdgcn_mfma_f32_16x16x32_bf16(Alo, Bg[g][ks][0], acc[g], 0, 0, 0);
#pragma unroll
            for (int g = 0; g < 4; ++g)
                acc[g] = __builtin_amdgcn_mfma_f32_16x16x32_bf16(Ahi, Bg[g][ks][0], acc[g], 0, 0, 0);
        }
#pragma unroll
        for (int r = 0; r < 4; ++r) {
            float i_ = sigm(acc[0][r]);
            float f_ = sigm(acc[1][r]);
            float gv = tanh_fast(acc[2][r]);
            float o_ = sigm(acc[3][r]);
            cst[r] = fmaf(f_, cst[r], i_ * gv);
            float h = o_ * tanh_fast(cst[r]);
            unsigned short phi, plo;
            split2(h, phi, plo);
            Nh[(m0c + r) * HS + jcol] = phi;
            Nl[(m0c + r) * HS + jcol] = plo;
        }
        { const unsigned short* th = Hh; Hh = Nh; Nh = (unsigned short*)th;
          const unsigned short* tl = Hl; Hl = Nl; Nl = (unsigned short*)tl; }
        __syncthreads();
    }

    // =================== decoder steps 1..59: two-pass burst ===================
    // Pass 1 completes the hacc chain by ~slot 28 of 60 (R11 had it at 58);
    // the shfl-reduce + partials + barrier then overlap the pass-2 gate drain.
#pragma unroll 1
    for (int it = 1; it < T_DEC; ++it) {
        f32x4 acc[4];
        f32x4 hacc = (f32x4){b1v, b1v, b1v, b1v};
#pragma unroll
        for (int g = 0; g < 4; ++g)
            acc[g] = (f32x4){bs1v[g], bs1v[g], bs1v[g], bs1v[g]};

        // ---- pass 1: hacc (12) interleaved with the Ahi*Bhi gate product (16) ----
#pragma unroll
        for (int ks = 0; ks < 4; ++ks) {
            frag8 Ahi = *(const frag8*)(Hh + fb + ks * 32);
            frag8 Alo = *(const frag8*)(Hl + fb + ks * 32);
            hacc = __builtin_amdgcn_mfma_f32_16x16x32_bf16(Ahi, Bw1[ks][1], hacc, 0, 0, 0);
            acc[0] = __builtin_amdgcn_mfma_f32_16x16x32_bf16(Ahi, Bg[0][ks][0], acc[0], 0, 0, 0);
            acc[1] = __builtin_amdgcn_mfma_f32_16x16x32_bf16(Ahi, Bg[1][ks][0], acc[1], 0, 0, 0);
            hacc = __builtin_amdgcn_mfma_f32_16x16x32_bf16(Alo, Bw1[ks][0], hacc, 0, 0, 0);
            acc[2] = __builtin_amdgcn_mfma_f32_16x16x32_bf16(Ahi, Bg[2][ks][0], acc[2], 0, 0, 0);
            acc[3] = __builtin_amdgcn_mfma_f32_16x16x32_bf16(Ahi, Bg[3][ks][0], acc[3], 0, 0, 0);
            hacc = __builtin_amdgcn_mfma_f32_16x16x32_bf16(Ahi, Bw1[ks][0], hacc, 0, 0, 0);
        }

        // hid=relu -> per-lane pred partials -> 16-lane shfl reduce (waits on hacc only)
        float p0[4], p1[4];
#pragma unroll
        for (int r = 0; r < 4; ++r) {
            float hv = fmaxf(hacc[r], 0.f);
            p0[r] = hv * w2v0;
            p1[r] = hv * w2v1;
        }

        // ---- pass 2: remaining gate products (32 MFMAs); A-frags re-read ----
#pragma unroll
        for (int ks = 0; ks < 4; ++ks) {
            frag8 Ahi = *(const frag8*)(Hh + fb + ks * 32);
            frag8 Alo = *(const frag8*)(Hl + fb + ks * 32);
#pragma unroll
            for (int g = 0; g < 4; ++g)
                acc[g] = __builtin_amdgcn_mfma_f32_16x16x32_bf16(Ahi, Bg[g][ks][1], acc[g], 0, 0, 0);
#pragma unroll
            for (int g = 0; g < 4; ++g)
                acc[g] = __builtin_amdgcn_mfma_f32_16x16x32_bf16(Alo, Bg[g][ks][0], acc[g], 0, 0, 0);
        }

#pragma unroll
        for (int mask = 1; mask < 16; mask <<= 1)
#pragma unroll
            for (int r = 0; r < 4; ++r) {
                p0[r] += __shfl_xor(p0[r], mask);
                p1[r] += __shfl_xor(p1[r], mask);
            }
#pragma unroll
        for (int r = 0; r < 4; ++r)
            part_s[w][m0c + r] = (float2){p0[r], p1[r]};   // same-value lanes: benign
        __syncthreads();   // partials visible (barrier 1) — gate MFMAs still draining

        // Every wave recomputes all 32 preds redundantly (register-neutral),
        // then shfl-broadcasts into lanes.
        {
            const int mm = (L >> 1) & 15;
            const int dd = L & 1;
            float s = dd ? b2v1 : b2v0;
#pragma unroll
            for (int wi = 0; wi < 8; ++wi)
                s += ((const float*)&part_s[wi][mm])[dd];
            if (w == 0 && L < 32)
                pred_buf[(mm * T_DEC + (it - 1)) * DIN + dd] = s;   // read only at final flush
#pragma unroll
            for (int r = 0; r < 4; ++r) {
                float pq0 = __shfl(s, (m0c + r) * 2);
                float pq1 = __shfl(s, (m0c + r) * 2 + 1);
#pragma unroll
                for (int g = 0; g < 4; ++g)
                    acc[g][r] += fmaf(pq1, we1v[g], pq0 * we0v[g]);
            }
        }

        // pointwise -> h_it
#pragma unroll
        for (int r = 0; r < 4; ++r) {
            float i_ = sigm(acc[0][r]);
            float f_ = sigm(acc[1][r]);
            float gv = tanh_fast(acc[2][r]);
            float o_ = sigm(acc[3][r]);
            cst[r] = fmaf(f_, cst[r], i_ * gv);
            float h = o_ * tanh_fast(cst[r]);
            unsigned short phi, plo;
            split2(h, phi, plo);
            Nh[(m0c + r) * HS + jcol] = phi;
            Nl[(m0c + r) * HS + jcol] = plo;
        }
        { const unsigned short* th = Hh; Hh = Nh; Nh = (unsigned short*)th;
          const unsigned short* tl = Hl; Hl = Nl; Nl = (unsigned short*)tl; }
        __syncthreads();   // new h visible (barrier 2)
    }

    // =================== tail: pred of the last decoder state ===================
    {
        f32x4 hacc = (f32x4){b1v, b1v, b1v, b1v};
#pragma unroll
        for (int ks = 0; ks < 4; ++ks) {
            frag8 Ahi = *(const frag8*)(Hh + fb + ks * 32);
            frag8 Alo = *(const frag8*)(Hl + fb + ks * 32);
            hacc = __builtin_amdgcn_mfma_f32_16x16x32_bf16(Ahi, Bw1[ks][1], hacc, 0, 0, 0);
            hacc = __builtin_amdgcn_mfma_f32_16x16x32_bf16(Alo, Bw1[ks][0], hacc, 0, 0, 0);
            hacc = __builtin_amdgcn_mfma_f32_16x16x32_bf16(Ahi, Bw1[ks][0], hacc, 0, 0, 0);
        }
        float p0[4], p1[4];
#pragma unroll
        for (int r = 0; r < 4; ++r) {
            float hv = fmaxf(hacc[r], 0.f);
            p0[r] = hv * w2v0;
            p1[r] = hv * w2v1;
        }
#pragma unroll
        for (int mask = 1; mask < 16; mask <<= 1)
#pragma unroll
            for (int r = 0; r < 4; ++r) {
                p0[r] += __shfl_xor(p0[r], mask);
                p1[r] += __shfl_xor(p1[r], mask);
            }
#pragma unroll
        for (int r = 0; r < 4; ++r)
            part_s[w][m0c + r] = (float2){p0[r], p1[r]};
        __syncthreads();
        if (w == 0 && L < 32) {
            const int mm = L >> 1;
            const int dd = L & 1;
            float s = dd ? b2v1 : b2v0;
#pragma unroll
            for (int wi = 0; wi < 8; ++wi)
                s += ((const float*)&part_s[wi][mm])[dd];
            pred_buf[(mm * T_DEC + (T_DEC - 1)) * DIN + dd] = s;
        }
        __syncthreads();
    }

    // ---- single coalesced flush of all preds ----
    for (int i = tid; i < MT * T_DEC * DIN; i += NTHR)
        out[(size_t)r0 * T_DEC * DIN + i] = pred_buf[i];
}

extern "C" void kernel_launch(void* const* d_in, const int* in_sizes, int n_in,
                              void* d_out, int out_size, void* d_ws, size_t ws_size,
                              hipStream_t stream) {
    const float* history = (const float*)d_in[0];
    const float* W_emb   = (const float*)d_in[1];
    const float* b_emb   = (const float*)d_in[2];
    const float* W_ih    = (const float*)d_in[3];
    const float* W_hh    = (const float*)d_in[4];
    const float* b_ih    = (const float*)d_in[5];
    const float* b_hh    = (const float*)d_in[6];
    const float* W1      = (const float*)d_in[7];
    const float* b1      = (const float*)d_in[8];
    const float* W2      = (const float*)d_in[9];
    const float* b2      = (const float*)d_in[10];
    float* out = (float*)d_out;
    (void)d_ws; (void)ws_size; (void)in_sizes; (void)n_in; (void)out_size;

    lstm_all<<<4096 / MT, NTHR, 0, stream>>>(history, W_emb, b_emb, W_ih, W_hh,
                                             b_ih, b_hh, W1, b1, W2, b2, out);
}